// Round 18
// baseline (286.121 us; speedup 1.0000x reference)
//
#include <hip/hip_runtime.h>
#include <hip/hip_bf16.h>
#include <cstddef>

#define N_NODES 50000
#define E_EDGES 800000
#define IN_F 512
#define HID_F 256
#define OUT_F 64
#define NCAT 320              // HID + OUT combined GEMM1 output cols
#define LN_EPS 1e-5f
#define L2_EPS 1e-12f

typedef unsigned short ushortT;
typedef __attribute__((ext_vector_type(8))) short short8;
typedef __attribute__((ext_vector_type(4))) float f32x4;

static __device__ __forceinline__ float clean0(float v) {
    return isfinite(v) ? v : 0.0f;
}

static __device__ __forceinline__ ushortT f2bf(float f) {
    __hip_bfloat16 h = __float2bfloat16(f);
    return *reinterpret_cast<ushortT*>(&h);
}

static __device__ __forceinline__ void bf8_to_f32(uint4 u, float f[8]) {
    f[0] = __uint_as_float(u.x << 16);
    f[1] = __uint_as_float(u.x & 0xFFFF0000u);
    f[2] = __uint_as_float(u.y << 16);
    f[3] = __uint_as_float(u.y & 0xFFFF0000u);
    f[4] = __uint_as_float(u.z << 16);
    f[5] = __uint_as_float(u.z & 0xFFFF0000u);
    f[6] = __uint_as_float(u.w << 16);
    f[7] = __uint_as_float(u.w & 0xFFFF0000u);
}

static __device__ __forceinline__ void bf4_to_f32v(uint2 u, float f[4]) {
    f[0] = __uint_as_float(u.x << 16);
    f[1] = __uint_as_float(u.x & 0xFFFF0000u);
    f[2] = __uint_as_float(u.y << 16);
    f[3] = __uint_as_float(u.y & 0xFFFF0000u);
}

// ---------------- prep: count_deg + wcvt fused ----------------
#define CNT_BLOCKS ((E_EDGES + 255) / 256)                       // 3125
#define WCVT_ELEMS (NCAT * IN_F + OUT_F * HID_F)                 // 180224
#define WCVT_BLOCKS ((WCVT_ELEMS + 255) / 256)                   // 704
__global__ __launch_bounds__(256) void prep_kernel(const int* __restrict__ dst,
                                                   int* __restrict__ deg,
                                                   const float* __restrict__ W1,
                                                   const float* __restrict__ Wskip,
                                                   const float* __restrict__ W2,
                                                   ushortT* __restrict__ Bf,
                                                   ushortT* __restrict__ W2f) {
    int bid = blockIdx.x;
    if (bid < CNT_BLOCKS) {
        int e = bid * 256 + threadIdx.x;
        if (e < E_EDGES) atomicAdd(&deg[dst[e]], 1);
    } else {
        int id = (bid - CNT_BLOCKS) * 256 + threadIdx.x;
        if (id < NCAT * IN_F) {
            int j = id & 7;
            int rem = id >> 3;
            int lane = rem & 63; rem >>= 6;
            int n = rem % 5;     rem /= 5;
            int kk = rem & 1;    rem >>= 1;
            int ks = rem & 7;
            int wc = rem >> 3;
            int col = wc * 80 + n * 16 + (lane & 15);
            int k = ks * 64 + kk * 32 + (lane >> 4) * 8 + j;
            float v = (col < HID_F) ? W1[(size_t)k * HID_F + col]
                                    : Wskip[(size_t)k * OUT_F + (col - HID_F)];
            Bf[id] = f2bf(v);
        } else if (id < WCVT_ELEMS) {
            int jj = id - NCAT * IN_F;
            int j = jj & 7;
            int rem = jj >> 3;
            int lane = rem & 63; rem >>= 6;
            int ks = rem & 7;
            int wc = rem >> 3;          // 0..3
            int col = wc * 16 + (lane & 15);
            int k = ks * 32 + (lane >> 4) * 8 + j;
            W2f[jj] = f2bf(W2[(size_t)k * OUT_F + col]);
        }
    }
}

// ---- parallel scan: scan1 (block prefix) + scan23 (apply, fused) ----
#define SB 1024
#define NSCAN_BLOCKS ((N_NODES + SB - 1) / SB)   // 49

__global__ __launch_bounds__(1024) void scan1_kernel(const int* __restrict__ deg,
                                                     float* __restrict__ dinv,
                                                     int* __restrict__ rowptr,
                                                     int* __restrict__ bsum) {
    __shared__ int buf[SB];
    const int t = threadIdx.x;
    const int idx = blockIdx.x * SB + t;
    int v = (idx < N_NODES) ? deg[idx] : 0;
    if (idx < N_NODES) dinv[idx] = rsqrtf((float)v + 1.0f);   // +1 self loop
    int x = v;
    buf[t] = x;
    __syncthreads();
    for (int off = 1; off < SB; off <<= 1) {
        int y = (t >= off) ? buf[t - off] : 0;
        __syncthreads();
        x += y;
        buf[t] = x;
        __syncthreads();
    }
    if (idx < N_NODES) rowptr[idx] = x - v;     // block-local exclusive prefix
    if (t == SB - 1) bsum[blockIdx.x] = x;      // block total
}

__global__ __launch_bounds__(256) void scan23_kernel(const int* __restrict__ bsum,
                                                     int* __restrict__ rowptr,
                                                     int* __restrict__ cursor) {
    __shared__ int boff_s[64];
    __shared__ int total_s;
    const int t = threadIdx.x;
    if (t < 64) {
        int v = (t < NSCAN_BLOCKS) ? bsum[t] : 0;
        int x = v;
        #pragma unroll
        for (int off = 1; off < 64; off <<= 1) {
            int y = __shfl_up(x, off, 64);
            if (t >= off) x += y;
        }
        boff_s[t] = x - v;                    // exclusive block offset
        if (t == NSCAN_BLOCKS - 1) total_s = x;
    }
    __syncthreads();
    int idx = blockIdx.x * 256 + t;
    if (idx < N_NODES) {
        int p = rowptr[idx] + boff_s[idx >> 10];
        rowptr[idx] = p;
        cursor[idx] = p;
    }
    if (blockIdx.x == 0 && t == 0) rowptr[N_NODES] = total_s;
}

// ---------------- fused GEMM1 v7 + scatter ----------------
#define G1_BM 64
#define NG1_BLOCKS ((N_NODES + G1_BM - 1) / G1_BM)     // 782
#define FUSED_BLOCKS (3 * NG1_BLOCKS)                  // 2346; %3==2 -> gemm1 (782 exactly)
#define APITCH 520            // bf16 elems per LDS row (1040 B), K=512 + 8 pad
#define MFMA_BF16 __builtin_amdgcn_mfma_f32_16x16x32_bf16
__global__ __launch_bounds__(512) void g1scat_kernel(const float* __restrict__ x,
                                                     const ushortT* __restrict__ Bf,
                                                     ushortT* __restrict__ h1b,
                                                     ushortT* __restrict__ skipb,
                                                     const int* __restrict__ src,
                                                     const int* __restrict__ dst,
                                                     int* __restrict__ cursor,
                                                     int* __restrict__ csr_src) {
    __shared__ ushortT As[G1_BM * APITCH];   // 66,560 B
    __shared__ float rn_s[G1_BM];

    const int bid = blockIdx.x;
    if (bid % 3 != 2) {
        // ---- scatter path (csr_src only) ----
        int sidx = (bid / 3) * 2 + (bid % 3);
        int e = sidx * 512 + threadIdx.x;
        if (e < E_EDGES) {
            int s = src[e], d = dst[e];
            int pos = atomicAdd(&cursor[d], 1);
            csr_src[pos] = s;
        }
        return;
    }

    // ---- gemm1 path (identical to v7) ----
    const int t = threadIdx.x;
    const int lane = t & 63;
    const int wid = t >> 6;                // 8 waves
    const int wr = wid >> 2, wc = wid & 3; // wave tile 32x80
    const int lr = lane & 15, lk = lane >> 4;
    const int brow = (bid / 3) * G1_BM;
    const int sr = t >> 3, sl = t & 7;     // staging: row (0..63), 8-elem slot

    int arow = brow + sr;
    arow = (arow < N_NODES) ? arow : (N_NODES - 1);
    const float* xrow = x + (size_t)arow * IN_F + sl * 8;

    // ---- fill phase ----
    float4 xa[16];
    #pragma unroll
    for (int c = 0; c < 8; ++c) {
        xa[2 * c]     = *(const float4*)(xrow + c * 64);
        xa[2 * c + 1] = *(const float4*)(xrow + c * 64 + 4);
    }
    float ss = 0.0f;
    #pragma unroll
    for (int c = 0; c < 8; ++c) {
        float cl[8];
        cl[0] = clean0(xa[2*c].x);   cl[1] = clean0(xa[2*c].y);
        cl[2] = clean0(xa[2*c].z);   cl[3] = clean0(xa[2*c].w);
        cl[4] = clean0(xa[2*c+1].x); cl[5] = clean0(xa[2*c+1].y);
        cl[6] = clean0(xa[2*c+1].z); cl[7] = clean0(xa[2*c+1].w);
        #pragma unroll
        for (int i = 0; i < 8; ++i) ss = fmaf(cl[i], cl[i], ss);
        uint4 au;
        au.x = (unsigned)f2bf(cl[0]) | ((unsigned)f2bf(cl[1]) << 16);
        au.y = (unsigned)f2bf(cl[2]) | ((unsigned)f2bf(cl[3]) << 16);
        au.z = (unsigned)f2bf(cl[4]) | ((unsigned)f2bf(cl[5]) << 16);
        au.w = (unsigned)f2bf(cl[6]) | ((unsigned)f2bf(cl[7]) << 16);
        *(uint4*)&As[sr * APITCH + c * 64 + sl * 8] = au;
    }
    ss += __shfl_xor(ss, 1);
    ss += __shfl_xor(ss, 2);
    ss += __shfl_xor(ss, 4);
    if (sl == 0) rn_s[sr] = 1.0f / fmaxf(sqrtf(ss), L2_EPS);
    __syncthreads();                        // the ONLY barrier before epilogue

    const ushortT* bbase = Bf + (size_t)wc * (8 * 2 * 5 * 64 * 8) + (size_t)lane * 8;
    f32x4 acc[2][5] = {};
    #pragma unroll 1
    for (int ks = 0; ks < 8; ++ks) {
        uint4 breg[2][5];
        #pragma unroll
        for (int kk = 0; kk < 2; ++kk)
            #pragma unroll
            for (int n = 0; n < 5; ++n)
                breg[kk][n] = *(const uint4*)(bbase + (size_t)(((ks * 2 + kk) * 5 + n)) * (64 * 8));
        short8 a[2][2];
        #pragma unroll
        for (int kk = 0; kk < 2; ++kk)
            #pragma unroll
            for (int m = 0; m < 2; ++m)
                a[kk][m] = *(const short8*)&As[(wr * 32 + m * 16 + lr) * APITCH + ks * 64 + kk * 32 + lk * 8];
        #pragma unroll
        for (int kk = 0; kk < 2; ++kk)
            #pragma unroll
            for (int m = 0; m < 2; ++m)
                #pragma unroll
                for (int n = 0; n < 5; ++n)
                    acc[m][n] = MFMA_BF16(a[kk][m], *(const short8*)&breg[kk][n], acc[m][n], 0, 0, 0);
    }

    #pragma unroll
    for (int m = 0; m < 2; ++m) {
        int row0 = wr * 32 + m * 16 + lk * 4;
        #pragma unroll
        for (int n = 0; n < 5; ++n) {
            int col = wc * 80 + n * 16 + lr;
            if (col < HID_F) {
                #pragma unroll
                for (int v = 0; v < 4; ++v) {
                    int grow = brow + row0 + v;
                    if (grow < N_NODES)
                        h1b[(size_t)grow * HID_F + col] = f2bf(acc[m][n][v] * rn_s[row0 + v]);
                }
            } else {
                int c2 = col - HID_F;
                #pragma unroll
                for (int v = 0; v < 4; ++v) {
                    int grow = brow + row0 + v;
                    if (grow < N_NODES)
                        skipb[(size_t)grow * OUT_F + c2] = f2bf(acc[m][n][v] * rn_s[row0 + v]);
                }
            }
        }
    }
}

// ---------------- fused agg1+LN+ReLU -> LDS -> GEMM2 -> h2b; 32 nodes/block ----------------
#define AG_BM 32
#define NAG_BLOCKS ((N_NODES + AG_BM - 1) / AG_BM)   // 1563
#define LPITCH 264            // ln_s row pitch in bf16 (528 B)
#define H2S_PITCH 72
__global__ __launch_bounds__(256, 8) void aggln_g2_kernel(const ushortT* __restrict__ h1b,
                                                          const float* __restrict__ dinv,
                                                          const int* __restrict__ rowptr,
                                                          const int* __restrict__ csr_src,
                                                          const float* __restrict__ b1,
                                                          const float* __restrict__ gamma,
                                                          const float* __restrict__ beta,
                                                          const ushortT* __restrict__ W2f,
                                                          ushortT* __restrict__ h2b) {
    __shared__ ushortT ln_s[AG_BM * LPITCH];     // 16,896 B; h2_s aliases first 4,608 B
    ushortT* h2_s = ln_s;

    const int t = threadIdx.x;
    const int brow = blockIdx.x * AG_BM;

    // ---- phase 1: agg + bias + LN + ReLU for 32 nodes (8 half-waves x 4 rounds) ----
    {
        const int h = t >> 5;       // half-wave 0..7
        const int l = t & 31;
        const uint4* hp = (const uint4*)h1b;
        #pragma unroll 1
        for (int p = 0; p < 4; ++p) {
            int nl = p * 8 + h;
            int node = brow + nl;
            uint4 res = make_uint4(0, 0, 0, 0);
            if (node < N_NODES) {
                float di = dinv[node];
                float a[8], g[8];
                bf8_to_f32(hp[(size_t)node * 32 + l], a);
                float ws = di * di;
                #pragma unroll
                for (int i = 0; i < 8; ++i) a[i] *= ws;

                int jb = rowptr[node], je = rowptr[node + 1];
                int j = jb;
                for (; j + 7 < je; j += 8) {
                    int s0 = csr_src[j],     s1 = csr_src[j + 1];
                    int s2 = csr_src[j + 2], s3 = csr_src[j + 3];
                    int s4 = csr_src[j + 4], s5 = csr_src[j + 5];
                    int s6 = csr_src[j + 6], s7 = csr_src[j + 7];
                    float w0 = dinv[s0] * di, w1 = dinv[s1] * di;
                    float w2 = dinv[s2] * di, w3 = dinv[s3] * di;
                    float w4 = dinv[s4] * di, w5 = dinv[s5] * di;
                    float w6 = dinv[s6] * di, w7 = dinv[s7] * di;
                    uint4 u0 = hp[(size_t)s0 * 32 + l];
                    uint4 u1 = hp[(size_t)s1 * 32 + l];
                    uint4 u2 = hp[(size_t)s2 * 32 + l];
                    uint4 u3 = hp[(size_t)s3 * 32 + l];
                    uint4 u4 = hp[(size_t)s4 * 32 + l];
                    uint4 u5 = hp[(size_t)s5 * 32 + l];
                    uint4 u6 = hp[(size_t)s6 * 32 + l];
                    uint4 u7 = hp[(size_t)s7 * 32 + l];
                    bf8_to_f32(u0, g);
                    #pragma unroll
                    for (int i = 0; i < 8; ++i) a[i] = fmaf(g[i], w0, a[i]);
                    bf8_to_f32(u1, g);
                    #pragma unroll
                    for (int i = 0; i < 8; ++i) a[i] = fmaf(g[i], w1, a[i]);
                    bf8_to_f32(u2, g);
                    #pragma unroll
                    for (int i = 0; i < 8; ++i) a[i] = fmaf(g[i], w2, a[i]);
                    bf8_to_f32(u3, g);
                    #pragma unroll
                    for (int i = 0; i < 8; ++i) a[i] = fmaf(g[i], w3, a[i]);
                    bf8_to_f32(u4, g);
                    #pragma unroll
                    for (int i = 0; i < 8; ++i) a[i] = fmaf(g[i], w4, a[i]);
                    bf8_to_f32(u5, g);
                    #pragma unroll
                    for (int i = 0; i < 8; ++i) a[i] = fmaf(g[i], w5, a[i]);
                    bf8_to_f32(u6, g);
                    #pragma unroll
                    for (int i = 0; i < 8; ++i) a[i] = fmaf(g[i], w6, a[i]);
                    bf8_to_f32(u7, g);
                    #pragma unroll
                    for (int i = 0; i < 8; ++i) a[i] = fmaf(g[i], w7, a[i]);
                }
                for (; j + 3 < je; j += 4) {
                    int s0 = csr_src[j], s1 = csr_src[j + 1];
                    int s2 = csr_src[j + 2], s3 = csr_src[j + 3];
                    float w0 = dinv[s0] * di, w1 = dinv[s1] * di;
                    float w2 = dinv[s2] * di, w3 = dinv[s3] * di;
                    uint4 u0 = hp[(size_t)s0 * 32 + l];
                    uint4 u1 = hp[(size_t)s1 * 32 + l];
                    uint4 u2 = hp[(size_t)s2 * 32 + l];
                    uint4 u3 = hp[(size_t)s3 * 32 + l];
                    bf8_to_f32(u0, g);
                    #pragma unroll
                    for (int i = 0; i < 8; ++i) a[i] = fmaf(g[i], w0, a[i]);
                    bf8_to_f32(u1, g);
                    #pragma unroll
                    for (int i = 0; i < 8; ++i) a[i] = fmaf(g[i], w1, a[i]);
                    bf8_to_f32(u2, g);
                    #pragma unroll
                    for (int i = 0; i < 8; ++i) a[i] = fmaf(g[i], w2, a[i]);
                    bf8_to_f32(u3, g);
                    #pragma unroll
                    for (int i = 0; i < 8; ++i) a[i] = fmaf(g[i], w3, a[i]);
                }
                for (; j < je; ++j) {
                    int s0 = csr_src[j];
                    float w0 = dinv[s0] * di;
                    bf8_to_f32(hp[(size_t)s0 * 32 + l], g);
                    #pragma unroll
                    for (int i = 0; i < 8; ++i) a[i] = fmaf(g[i], w0, a[i]);
                }

                float4 ba = *(const float4*)(b1 + l * 8);
                float4 bb = *(const float4*)(b1 + l * 8 + 4);
                a[0] += ba.x; a[1] += ba.y; a[2] += ba.z; a[3] += ba.w;
                a[4] += bb.x; a[5] += bb.y; a[6] += bb.z; a[7] += bb.w;

                float s = 0.0f, s2 = 0.0f;
                #pragma unroll
                for (int i = 0; i < 8; ++i) { s += a[i]; s2 = fmaf(a[i], a[i], s2); }
                #pragma unroll
                for (int off = 16; off > 0; off >>= 1) {
                    s += __shfl_xor(s, off);
                    s2 += __shfl_xor(s2, off);
                }
                float mu = s * (1.0f / HID_F);
                float var = s2 * (1.0f / HID_F) - mu * mu;
                float rs = rsqrtf(var + LN_EPS);

                float4 ga = *(const float4*)(gamma + l * 8);
                float4 gb = *(const float4*)(gamma + l * 8 + 4);
                float4 ea = *(const float4*)(beta + l * 8);
                float4 eb = *(const float4*)(beta + l * 8 + 4);
                float gm[8] = {ga.x, ga.y, ga.z, ga.w, gb.x, gb.y, gb.z, gb.w};
                float be[8] = {ea.x, ea.y, ea.z, ea.w, eb.x, eb.y, eb.z, eb.w};
                ushortT o[8];
                #pragma unroll
                for (int i = 0; i < 8; ++i)
                    o[i] = f2bf(fmaxf(0.0f, (a[i] - mu) * rs * gm[i] + be[i]));
                res = *(uint4*)o;
            }
            *(uint4*)&ln_s[nl * LPITCH + l * 8] = res;
        }
    }
    __syncthreads();

    // ---- phase 2: gemm2 [32x256] @ [256x64], 4 waves, wave tile 32x16 ----
    f32x4 acc[2] = {};
    {
        const int lane = t & 63;
        const int wc = t >> 6;            // 4 waves
        const int lr = lane & 15, lk = lane >> 4;
        const ushortT* wbase = W2f + ((size_t)wc * 8 * 64 + lane) * 8;

        #pragma unroll
        for (int ks = 0; ks < 8; ++ks) {
            uint4 b = *(const uint4*)(wbase + (size_t)ks * (64 * 8));
            short8 a0 = *(const short8*)&ln_s[(lr) * LPITCH + ks * 32 + lk * 8];
            short8 a1 = *(const short8*)&ln_s[(16 + lr) * LPITCH + ks * 32 + lk * 8];
            acc[0] = MFMA_BF16(a0, *(const short8*)&b, acc[0], 0, 0, 0);
            acc[1] = MFMA_BF16(a1, *(const short8*)&b, acc[1], 0, 0, 0);
        }
    }
    __syncthreads();   // all ln_s reads done -> safe to overwrite (h2_s alias)

    {
        const int lane = t & 63;
        const int wc = t >> 6;
        const int lr = lane & 15, lk = lane >> 4;
        // stage to LDS: row = m*16 + lk*4 + v ; col = wc*16 + lr
        #pragma unroll
        for (int m = 0; m < 2; ++m) {
            int row0 = m * 16 + lk * 4;
            int col = wc * 16 + lr;
            #pragma unroll
            for (int v = 0; v < 4; ++v)
                h2_s[(row0 + v) * H2S_PITCH + col] = f2bf(acc[m][v]);
        }
    }
    __syncthreads();

    // coalesced store: 32 rows x 128 B = 256 uint4 (one per thread)
    {
        int row = t >> 3, s8 = t & 7;
        int grow = brow + row;
        if (grow < N_NODES)
            *(uint4*)(h2b + (size_t)grow * OUT_F + s8 * 8) =
                *(const uint4*)&h2_s[row * H2S_PITCH + s8 * 8];
    }
}

// ---------------- aggregation 2: quarter-wave per node, bf16 h2 + bf16 skip ----------------
__global__ __launch_bounds__(256, 8) void agg2_gather_kernel(const ushortT* __restrict__ h2b,
                                                             const ushortT* __restrict__ skipb,
                                                             const float* __restrict__ b2,
                                                             const float* __restrict__ dinv,
                                                             const int* __restrict__ rowptr,
                                                             const int* __restrict__ csr_src,
                                                             float* __restrict__ out) {
    int node = blockIdx.x * 16 + (threadIdx.x >> 4);
    if (node >= N_NODES) return;
    int l = threadIdx.x & 15;
    const uint2* hp = (const uint2*)h2b;       // 16 uint2 (8B = 4 bf16) per row

    float di = dinv[node];
    float ws = di * di;
    float a[4], g[4];
    bf4_to_f32v(hp[(size_t)node * 16 + l], a);
    float ax = a[0] * ws, ay = a[1] * ws, az = a[2] * ws, aw = a[3] * ws;

    int jb = rowptr[node], je = rowptr[node + 1];
    int j = jb;
    for (; j + 7 < je; j += 8) {
        int s0 = csr_src[j],     s1 = csr_src[j + 1], s2 = csr_src[j + 2], s3 = csr_src[j + 3];
        int s4 = csr_src[j + 4], s5 = csr_src[j + 5], s6 = csr_src[j + 6], s7 = csr_src[j + 7];
        float w0 = dinv[s0] * di, w1 = dinv[s1] * di, w2 = dinv[s2] * di, w3 = dinv[s3] * di;
        float w4 = dinv[s4] * di, w5 = dinv[s5] * di, w6 = dinv[s6] * di, w7 = dinv[s7] * di;
        uint2 u0 = hp[(size_t)s0 * 16 + l];
        uint2 u1 = hp[(size_t)s1 * 16 + l];
        uint2 u2 = hp[(size_t)s2 * 16 + l];
        uint2 u3 = hp[(size_t)s3 * 16 + l];
        uint2 u4 = hp[(size_t)s4 * 16 + l];
        uint2 u5 = hp[(size_t)s5 * 16 + l];
        uint2 u6 = hp[(size_t)s6 * 16 + l];
        uint2 u7 = hp[(size_t)s7 * 16 + l];
        bf4_to_f32v(u0, g);
        ax = fmaf(g[0], w0, ax); ay = fmaf(g[1], w0, ay); az = fmaf(g[2], w0, az); aw = fmaf(g[3], w0, aw);
        bf4_to_f32v(u1, g);
        ax = fmaf(g[0], w1, ax); ay = fmaf(g[1], w1, ay); az = fmaf(g[2], w1, az); aw = fmaf(g[3], w1, aw);
        bf4_to_f32v(u2, g);
        ax = fmaf(g[0], w2, ax); ay = fmaf(g[1], w2, ay); az = fmaf(g[2], w2, az); aw = fmaf(g[3], w2, aw);
        bf4_to_f32v(u3, g);
        ax = fmaf(g[0], w3, ax); ay = fmaf(g[1], w3, ay); az = fmaf(g[2], w3, az); aw = fmaf(g[3], w3, aw);
        bf4_to_f32v(u4, g);
        ax = fmaf(g[0], w4, ax); ay = fmaf(g[1], w4, ay); az = fmaf(g[2], w4, az); aw = fmaf(g[3], w4, aw);
        bf4_to_f32v(u5, g);
        ax = fmaf(g[0], w5, ax); ay = fmaf(g[1], w5, ay); az = fmaf(g[2], w5, az); aw = fmaf(g[3], w5, aw);
        bf4_to_f32v(u6, g);
        ax = fmaf(g[0], w6, ax); ay = fmaf(g[1], w6, ay); az = fmaf(g[2], w6, az); aw = fmaf(g[3], w6, aw);
        bf4_to_f32v(u7, g);
        ax = fmaf(g[0], w7, ax); ay = fmaf(g[1], w7, ay); az = fmaf(g[2], w7, az); aw = fmaf(g[3], w7, aw);
    }
    for (; j + 3 < je; j += 4) {
        int s0 = csr_src[j], s1 = csr_src[j + 1], s2 = csr_src[j + 2], s3 = csr_src[j + 3];
        float w0 = dinv[s0] * di, w1 = dinv[s1] * di, w2 = dinv[s2] * di, w3 = dinv[s3] * di;
        uint2 u0 = hp[(size_t)s0 * 16 + l];
        uint2 u1 = hp[(size_t)s1 * 16 + l];
        uint2 u2 = hp[(size_t)s2 * 16 + l];
        uint2 u3 = hp[(size_t)s3 * 16 + l];
        bf4_to_f32v(u0, g);
        ax = fmaf(g[0], w0, ax); ay = fmaf(g[1], w0, ay); az = fmaf(g[2], w0, az); aw = fmaf(g[3], w0, aw);
        bf4_to_f32v(u1, g);
        ax = fmaf(g[0], w1, ax); ay = fmaf(g[1], w1, ay); az = fmaf(g[2], w1, az); aw = fmaf(g[3], w1, aw);
        bf4_to_f32v(u2, g);
        ax = fmaf(g[0], w2, ax); ay = fmaf(g[1], w2, ay); az = fmaf(g[2], w2, az); aw = fmaf(g[3], w2, aw);
        bf4_to_f32v(u3, g);
        ax = fmaf(g[0], w3, ax); ay = fmaf(g[1], w3, ay); az = fmaf(g[2], w3, az); aw = fmaf(g[3], w3, aw);
    }
    for (; j < je; ++j) {
        int s0 = csr_src[j];
        float w0 = dinv[s0] * di;
        bf4_to_f32v(hp[(size_t)s0 * 16 + l], g);
        ax = fmaf(g[0], w0, ax); ay = fmaf(g[1], w0, ay); az = fmaf(g[2], w0, az); aw = fmaf(g[3], w0, aw);
    }

    float sk[4];
    bf4_to_f32v(((const uint2*)skipb)[(size_t)node * 16 + l], sk);
    float4 bb = ((const float4*)b2)[l];
    float r[4] = {ax + sk[0] + bb.x, ay + sk[1] + bb.y, az + sk[2] + bb.z, aw + sk[3] + bb.w};
    #pragma unroll
    for (int i = 0; i < 4; ++i) {
        float v = r[i];
        if (isnan(v)) v = 0.0f;
        else if (isinf(v)) v = (v > 0.0f) ? 20.0f : -20.0f;
        r[i] = v;
    }
    ((float4*)out)[(size_t)node * 16 + l] = make_float4(r[0], r[1], r[2], r[3]);
}

extern "C" void kernel_launch(void* const* d_in, const int* in_sizes, int n_in,
                              void* d_out, int out_size, void* d_ws, size_t ws_size,
                              hipStream_t stream) {
    const float* x     = (const float*)d_in[0];
    const int*   ei    = (const int*)d_in[1];
    const float* W1    = (const float*)d_in[2];
    const float* b1    = (const float*)d_in[3];
    const float* gamma = (const float*)d_in[4];
    const float* beta  = (const float*)d_in[5];
    const float* W2    = (const float*)d_in[6];
    const float* b2    = (const float*)d_in[7];
    const float* Wskip = (const float*)d_in[8];
    float* out = (float*)d_out;

    const int* src = ei;
    const int* dst = ei + E_EDGES;

    // ws layout
    ushortT* h1b   = (ushortT*)d_ws;                       // N*256 bf16
    ushortT* h2b   = h1b + (size_t)N_NODES * HID_F;        // N*64 bf16
    ushortT* skipb = h2b + (size_t)N_NODES * OUT_F;        // N*64 bf16
    float* dinv    = (float*)(skipb + (size_t)N_NODES * OUT_F);  // N
    ushortT* Bf    = (ushortT*)(dinv + N_NODES);           // 320*512 (fragment order)
    ushortT* W2f   = Bf + (size_t)NCAT * IN_F;             // 64*256 (fragment order)
    int* deg       = (int*)(W2f + (size_t)OUT_F * HID_F);  // N
    int* rowptr    = deg + N_NODES;                        // N+1
    int* cursor    = rowptr + N_NODES + 1;                 // N
    int* csr_src   = cursor + N_NODES;                     // E
    int* bsum      = csr_src + E_EDGES;                    // NSCAN_BLOCKS

    // ---- prep: memset + fused count_deg|wcvt ----
    hipMemsetAsync(deg, 0, N_NODES * sizeof(int), stream);
    prep_kernel<<<CNT_BLOCKS + WCVT_BLOCKS, 256, 0, stream>>>(dst, deg, W1, Wskip, W2,
                                                              Bf, W2f);

    // ---- scan chain (dinv + rowptr + cursor) ----
    scan1_kernel<<<NSCAN_BLOCKS, SB, 0, stream>>>(deg, dinv, rowptr, bsum);
    scan23_kernel<<<(N_NODES + 255) / 256, 256, 0, stream>>>(bsum, rowptr, cursor);

    // ---- fused GEMM1 + scatter ----
    g1scat_kernel<<<FUSED_BLOCKS, 512, 0, stream>>>(x, Bf, h1b, skipb, src, dst,
                                                    cursor, csr_src);

    // ---- fused agg1 + LN + ReLU + GEMM2 -> h2b (32 nodes/block, 1563 blocks) ----
    aggln_g2_kernel<<<NAG_BLOCKS, 256, 0, stream>>>(h1b, dinv, rowptr, csr_src,
                                                    b1, gamma, beta, W2f, h2b);

    // ---- aggregation 2 (bf16 gather, inline weights, fused epilogue) ----
    agg2_gather_kernel<<<(N_NODES + 15) / 16, 256, 0, stream>>>(h2b, skipb, b2, dinv,
                                                                rowptr, csr_src, out);
}

// Round 19
// 204.286 us; speedup vs baseline: 1.4006x; 1.4006x over previous
//
#include <hip/hip_runtime.h>
#include <hip/hip_bf16.h>
#include <cstddef>

#define N_NODES 50000
#define E_EDGES 800000
#define IN_F 512
#define HID_F 256
#define OUT_F 64
#define NCAT 320              // HID + OUT combined GEMM1 output cols
#define LN_EPS 1e-5f
#define L2_EPS 1e-12f

typedef unsigned short ushortT;
typedef __attribute__((ext_vector_type(8))) short short8;
typedef __attribute__((ext_vector_type(4))) float f32x4;

static __device__ __forceinline__ float clean0(float v) {
    return isfinite(v) ? v : 0.0f;
}

static __device__ __forceinline__ ushortT f2bf(float f) {
    __hip_bfloat16 h = __float2bfloat16(f);
    return *reinterpret_cast<ushortT*>(&h);
}

static __device__ __forceinline__ void bf8_to_f32(uint4 u, float f[8]) {
    f[0] = __uint_as_float(u.x << 16);
    f[1] = __uint_as_float(u.x & 0xFFFF0000u);
    f[2] = __uint_as_float(u.y << 16);
    f[3] = __uint_as_float(u.y & 0xFFFF0000u);
    f[4] = __uint_as_float(u.z << 16);
    f[5] = __uint_as_float(u.z & 0xFFFF0000u);
    f[6] = __uint_as_float(u.w << 16);
    f[7] = __uint_as_float(u.w & 0xFFFF0000u);
}

static __device__ __forceinline__ void bf4_to_f32v(uint2 u, float f[4]) {
    f[0] = __uint_as_float(u.x << 16);
    f[1] = __uint_as_float(u.x & 0xFFFF0000u);
    f[2] = __uint_as_float(u.y << 16);
    f[3] = __uint_as_float(u.y & 0xFFFF0000u);
}

// ---------------- prep: count_deg + wcvt fused ----------------
#define CNT_BLOCKS ((E_EDGES + 255) / 256)                       // 3125
#define WCVT_ELEMS (NCAT * IN_F + OUT_F * HID_F)                 // 180224
#define WCVT_BLOCKS ((WCVT_ELEMS + 255) / 256)                   // 704
__global__ __launch_bounds__(256) void prep_kernel(const int* __restrict__ dst,
                                                   int* __restrict__ deg,
                                                   const float* __restrict__ W1,
                                                   const float* __restrict__ Wskip,
                                                   const float* __restrict__ W2,
                                                   ushortT* __restrict__ Bf,
                                                   ushortT* __restrict__ W2f) {
    int bid = blockIdx.x;
    if (bid < CNT_BLOCKS) {
        int e = bid * 256 + threadIdx.x;
        if (e < E_EDGES) atomicAdd(&deg[dst[e]], 1);
    } else {
        int id = (bid - CNT_BLOCKS) * 256 + threadIdx.x;
        if (id < NCAT * IN_F) {
            int j = id & 7;
            int rem = id >> 3;
            int lane = rem & 63; rem >>= 6;
            int n = rem % 5;     rem /= 5;
            int kk = rem & 1;    rem >>= 1;
            int ks = rem & 7;
            int wc = rem >> 3;
            int col = wc * 80 + n * 16 + (lane & 15);
            int k = ks * 64 + kk * 32 + (lane >> 4) * 8 + j;
            float v = (col < HID_F) ? W1[(size_t)k * HID_F + col]
                                    : Wskip[(size_t)k * OUT_F + (col - HID_F)];
            Bf[id] = f2bf(v);
        } else if (id < WCVT_ELEMS) {
            int jj = id - NCAT * IN_F;
            int j = jj & 7;
            int rem = jj >> 3;
            int lane = rem & 63; rem >>= 6;
            int ks = rem & 7;
            int wc = rem >> 3;          // 0..3
            int col = wc * 16 + (lane & 15);
            int k = ks * 32 + (lane >> 4) * 8 + j;
            W2f[jj] = f2bf(W2[(size_t)k * OUT_F + col]);
        }
    }
}

// ---- parallel scan: scan1 (block prefix) + scan23 (apply, fused) ----
#define SB 1024
#define NSCAN_BLOCKS ((N_NODES + SB - 1) / SB)   // 49

__global__ __launch_bounds__(1024) void scan1_kernel(const int* __restrict__ deg,
                                                     float* __restrict__ dinv,
                                                     int* __restrict__ rowptr,
                                                     int* __restrict__ bsum) {
    __shared__ int buf[SB];
    const int t = threadIdx.x;
    const int idx = blockIdx.x * SB + t;
    int v = (idx < N_NODES) ? deg[idx] : 0;
    if (idx < N_NODES) dinv[idx] = rsqrtf((float)v + 1.0f);   // +1 self loop
    int x = v;
    buf[t] = x;
    __syncthreads();
    for (int off = 1; off < SB; off <<= 1) {
        int y = (t >= off) ? buf[t - off] : 0;
        __syncthreads();
        x += y;
        buf[t] = x;
        __syncthreads();
    }
    if (idx < N_NODES) rowptr[idx] = x - v;     // block-local exclusive prefix
    if (t == SB - 1) bsum[blockIdx.x] = x;      // block total
}

__global__ __launch_bounds__(256) void scan23_kernel(const int* __restrict__ bsum,
                                                     int* __restrict__ rowptr,
                                                     int* __restrict__ cursor) {
    __shared__ int boff_s[64];
    __shared__ int total_s;
    const int t = threadIdx.x;
    if (t < 64) {
        int v = (t < NSCAN_BLOCKS) ? bsum[t] : 0;
        int x = v;
        #pragma unroll
        for (int off = 1; off < 64; off <<= 1) {
            int y = __shfl_up(x, off, 64);
            if (t >= off) x += y;
        }
        boff_s[t] = x - v;                    // exclusive block offset
        if (t == NSCAN_BLOCKS - 1) total_s = x;
    }
    __syncthreads();
    int idx = blockIdx.x * 256 + t;
    if (idx < N_NODES) {
        int p = rowptr[idx] + boff_s[idx >> 10];
        rowptr[idx] = p;
        cursor[idx] = p;
    }
    if (blockIdx.x == 0 && t == 0) rowptr[N_NODES] = total_s;
}

// ---------------- fused GEMM1 v7 + scatter ----------------
#define G1_BM 64
#define NG1_BLOCKS ((N_NODES + G1_BM - 1) / G1_BM)     // 782
#define FUSED_BLOCKS (3 * NG1_BLOCKS)                  // 2346; %3==2 -> gemm1 (782 exactly)
#define APITCH 520            // bf16 elems per LDS row (1040 B), K=512 + 8 pad
#define MFMA_BF16 __builtin_amdgcn_mfma_f32_16x16x32_bf16
__global__ __launch_bounds__(512) void g1scat_kernel(const float* __restrict__ x,
                                                     const ushortT* __restrict__ Bf,
                                                     ushortT* __restrict__ h1b,
                                                     ushortT* __restrict__ skipb,
                                                     const int* __restrict__ src,
                                                     const int* __restrict__ dst,
                                                     int* __restrict__ cursor,
                                                     int* __restrict__ csr_src) {
    __shared__ ushortT As[G1_BM * APITCH];   // 66,560 B
    __shared__ float rn_s[G1_BM];

    const int bid = blockIdx.x;
    if (bid % 3 != 2) {
        // ---- scatter path (csr_src only) ----
        int sidx = (bid / 3) * 2 + (bid % 3);
        int e = sidx * 512 + threadIdx.x;
        if (e < E_EDGES) {
            int s = src[e], d = dst[e];
            int pos = atomicAdd(&cursor[d], 1);
            csr_src[pos] = s;
        }
        return;
    }

    // ---- gemm1 path (identical to v7) ----
    const int t = threadIdx.x;
    const int lane = t & 63;
    const int wid = t >> 6;                // 8 waves
    const int wr = wid >> 2, wc = wid & 3; // wave tile 32x80
    const int lr = lane & 15, lk = lane >> 4;
    const int brow = (bid / 3) * G1_BM;
    const int sr = t >> 3, sl = t & 7;     // staging: row (0..63), 8-elem slot

    int arow = brow + sr;
    arow = (arow < N_NODES) ? arow : (N_NODES - 1);
    const float* xrow = x + (size_t)arow * IN_F + sl * 8;

    // ---- fill phase ----
    float4 xa[16];
    #pragma unroll
    for (int c = 0; c < 8; ++c) {
        xa[2 * c]     = *(const float4*)(xrow + c * 64);
        xa[2 * c + 1] = *(const float4*)(xrow + c * 64 + 4);
    }
    float ss = 0.0f;
    #pragma unroll
    for (int c = 0; c < 8; ++c) {
        float cl[8];
        cl[0] = clean0(xa[2*c].x);   cl[1] = clean0(xa[2*c].y);
        cl[2] = clean0(xa[2*c].z);   cl[3] = clean0(xa[2*c].w);
        cl[4] = clean0(xa[2*c+1].x); cl[5] = clean0(xa[2*c+1].y);
        cl[6] = clean0(xa[2*c+1].z); cl[7] = clean0(xa[2*c+1].w);
        #pragma unroll
        for (int i = 0; i < 8; ++i) ss = fmaf(cl[i], cl[i], ss);
        uint4 au;
        au.x = (unsigned)f2bf(cl[0]) | ((unsigned)f2bf(cl[1]) << 16);
        au.y = (unsigned)f2bf(cl[2]) | ((unsigned)f2bf(cl[3]) << 16);
        au.z = (unsigned)f2bf(cl[4]) | ((unsigned)f2bf(cl[5]) << 16);
        au.w = (unsigned)f2bf(cl[6]) | ((unsigned)f2bf(cl[7]) << 16);
        *(uint4*)&As[sr * APITCH + c * 64 + sl * 8] = au;
    }
    ss += __shfl_xor(ss, 1);
    ss += __shfl_xor(ss, 2);
    ss += __shfl_xor(ss, 4);
    if (sl == 0) rn_s[sr] = 1.0f / fmaxf(sqrtf(ss), L2_EPS);
    __syncthreads();                        // the ONLY barrier before epilogue

    const ushortT* bbase = Bf + (size_t)wc * (8 * 2 * 5 * 64 * 8) + (size_t)lane * 8;
    f32x4 acc[2][5] = {};
    #pragma unroll 1
    for (int ks = 0; ks < 8; ++ks) {
        uint4 breg[2][5];
        #pragma unroll
        for (int kk = 0; kk < 2; ++kk)
            #pragma unroll
            for (int n = 0; n < 5; ++n)
                breg[kk][n] = *(const uint4*)(bbase + (size_t)(((ks * 2 + kk) * 5 + n)) * (64 * 8));
        short8 a[2][2];
        #pragma unroll
        for (int kk = 0; kk < 2; ++kk)
            #pragma unroll
            for (int m = 0; m < 2; ++m)
                a[kk][m] = *(const short8*)&As[(wr * 32 + m * 16 + lr) * APITCH + ks * 64 + kk * 32 + lk * 8];
        #pragma unroll
        for (int kk = 0; kk < 2; ++kk)
            #pragma unroll
            for (int m = 0; m < 2; ++m)
                #pragma unroll
                for (int n = 0; n < 5; ++n)
                    acc[m][n] = MFMA_BF16(a[kk][m], *(const short8*)&breg[kk][n], acc[m][n], 0, 0, 0);
    }

    #pragma unroll
    for (int m = 0; m < 2; ++m) {
        int row0 = wr * 32 + m * 16 + lk * 4;
        #pragma unroll
        for (int n = 0; n < 5; ++n) {
            int col = wc * 80 + n * 16 + lr;
            if (col < HID_F) {
                #pragma unroll
                for (int v = 0; v < 4; ++v) {
                    int grow = brow + row0 + v;
                    if (grow < N_NODES)
                        h1b[(size_t)grow * HID_F + col] = f2bf(acc[m][n][v] * rn_s[row0 + v]);
                }
            } else {
                int c2 = col - HID_F;
                #pragma unroll
                for (int v = 0; v < 4; ++v) {
                    int grow = brow + row0 + v;
                    if (grow < N_NODES)
                        skipb[(size_t)grow * OUT_F + c2] = f2bf(acc[m][n][v] * rn_s[row0 + v]);
                }
            }
        }
    }
}

// ---------------- fused agg1+LN+ReLU -> LDS -> GEMM2 -> h2b; 32 nodes/block ----------------
#define AG_BM 32
#define NAG_BLOCKS ((N_NODES + AG_BM - 1) / AG_BM)   // 1563
#define LPITCH 264            // ln_s row pitch in bf16 (528 B)
#define H2S_PITCH 72
__global__ __launch_bounds__(256) void aggln_g2_kernel(const ushortT* __restrict__ h1b,
                                                       const float* __restrict__ dinv,
                                                       const int* __restrict__ rowptr,
                                                       const int* __restrict__ csr_src,
                                                       const float* __restrict__ b1,
                                                       const float* __restrict__ gamma,
                                                       const float* __restrict__ beta,
                                                       const ushortT* __restrict__ W2f,
                                                       ushortT* __restrict__ h2b) {
    __shared__ ushortT ln_s[AG_BM * LPITCH];     // 16,896 B; h2_s aliases first 4,608 B
    ushortT* h2_s = ln_s;

    const int t = threadIdx.x;
    const int brow = blockIdx.x * AG_BM;

    // ---- phase 1: agg + bias + LN + ReLU for 32 nodes (8 half-waves x 4 rounds) ----
    {
        const int h = t >> 5;       // half-wave 0..7
        const int l = t & 31;
        const uint4* hp = (const uint4*)h1b;
        #pragma unroll 1
        for (int p = 0; p < 4; ++p) {
            int nl = p * 8 + h;
            int node = brow + nl;
            uint4 res = make_uint4(0, 0, 0, 0);
            if (node < N_NODES) {
                float di = dinv[node];
                float a[8], g[8];
                bf8_to_f32(hp[(size_t)node * 32 + l], a);
                float ws = di * di;
                #pragma unroll
                for (int i = 0; i < 8; ++i) a[i] *= ws;

                int jb = rowptr[node], je = rowptr[node + 1];
                int j = jb;
                for (; j + 3 < je; j += 4) {
                    int s0 = csr_src[j], s1 = csr_src[j + 1];
                    int s2 = csr_src[j + 2], s3 = csr_src[j + 3];
                    float w0 = dinv[s0] * di, w1 = dinv[s1] * di;
                    float w2 = dinv[s2] * di, w3 = dinv[s3] * di;
                    uint4 u0 = hp[(size_t)s0 * 32 + l];
                    uint4 u1 = hp[(size_t)s1 * 32 + l];
                    uint4 u2 = hp[(size_t)s2 * 32 + l];
                    uint4 u3 = hp[(size_t)s3 * 32 + l];
                    bf8_to_f32(u0, g);
                    #pragma unroll
                    for (int i = 0; i < 8; ++i) a[i] = fmaf(g[i], w0, a[i]);
                    bf8_to_f32(u1, g);
                    #pragma unroll
                    for (int i = 0; i < 8; ++i) a[i] = fmaf(g[i], w1, a[i]);
                    bf8_to_f32(u2, g);
                    #pragma unroll
                    for (int i = 0; i < 8; ++i) a[i] = fmaf(g[i], w2, a[i]);
                    bf8_to_f32(u3, g);
                    #pragma unroll
                    for (int i = 0; i < 8; ++i) a[i] = fmaf(g[i], w3, a[i]);
                }
                for (; j < je; ++j) {
                    int s0 = csr_src[j];
                    float w0 = dinv[s0] * di;
                    bf8_to_f32(hp[(size_t)s0 * 32 + l], g);
                    #pragma unroll
                    for (int i = 0; i < 8; ++i) a[i] = fmaf(g[i], w0, a[i]);
                }

                float4 ba = *(const float4*)(b1 + l * 8);
                float4 bb = *(const float4*)(b1 + l * 8 + 4);
                a[0] += ba.x; a[1] += ba.y; a[2] += ba.z; a[3] += ba.w;
                a[4] += bb.x; a[5] += bb.y; a[6] += bb.z; a[7] += bb.w;

                float s = 0.0f, s2 = 0.0f;
                #pragma unroll
                for (int i = 0; i < 8; ++i) { s += a[i]; s2 = fmaf(a[i], a[i], s2); }
                #pragma unroll
                for (int off = 16; off > 0; off >>= 1) {
                    s += __shfl_xor(s, off);
                    s2 += __shfl_xor(s2, off);
                }
                float mu = s * (1.0f / HID_F);
                float var = s2 * (1.0f / HID_F) - mu * mu;
                float rs = rsqrtf(var + LN_EPS);

                float4 ga = *(const float4*)(gamma + l * 8);
                float4 gb = *(const float4*)(gamma + l * 8 + 4);
                float4 ea = *(const float4*)(beta + l * 8);
                float4 eb = *(const float4*)(beta + l * 8 + 4);
                float gm[8] = {ga.x, ga.y, ga.z, ga.w, gb.x, gb.y, gb.z, gb.w};
                float be[8] = {ea.x, ea.y, ea.z, ea.w, eb.x, eb.y, eb.z, eb.w};
                ushortT o[8];
                #pragma unroll
                for (int i = 0; i < 8; ++i)
                    o[i] = f2bf(fmaxf(0.0f, (a[i] - mu) * rs * gm[i] + be[i]));
                res = *(uint4*)o;
            }
            *(uint4*)&ln_s[nl * LPITCH + l * 8] = res;
        }
    }
    __syncthreads();

    // ---- phase 2: gemm2 [32x256] @ [256x64], 4 waves, wave tile 32x16 ----
    f32x4 acc[2] = {};
    {
        const int lane = t & 63;
        const int wc = t >> 6;            // 4 waves
        const int lr = lane & 15, lk = lane >> 4;
        const ushortT* wbase = W2f + ((size_t)wc * 8 * 64 + lane) * 8;

        #pragma unroll
        for (int ks = 0; ks < 8; ++ks) {
            uint4 b = *(const uint4*)(wbase + (size_t)ks * (64 * 8));
            short8 a0 = *(const short8*)&ln_s[(lr) * LPITCH + ks * 32 + lk * 8];
            short8 a1 = *(const short8*)&ln_s[(16 + lr) * LPITCH + ks * 32 + lk * 8];
            acc[0] = MFMA_BF16(a0, *(const short8*)&b, acc[0], 0, 0, 0);
            acc[1] = MFMA_BF16(a1, *(const short8*)&b, acc[1], 0, 0, 0);
        }
    }
    __syncthreads();   // all ln_s reads done -> safe to overwrite (h2_s alias)

    {
        const int lane = t & 63;
        const int wc = t >> 6;
        const int lr = lane & 15, lk = lane >> 4;
        // stage to LDS: row = m*16 + lk*4 + v ; col = wc*16 + lr
        #pragma unroll
        for (int m = 0; m < 2; ++m) {
            int row0 = m * 16 + lk * 4;
            int col = wc * 16 + lr;
            #pragma unroll
            for (int v = 0; v < 4; ++v)
                h2_s[(row0 + v) * H2S_PITCH + col] = f2bf(acc[m][v]);
        }
    }
    __syncthreads();

    // coalesced store: 32 rows x 128 B = 256 uint4 (one per thread)
    {
        int row = t >> 3, s8 = t & 7;
        int grow = brow + row;
        if (grow < N_NODES)
            *(uint4*)(h2b + (size_t)grow * OUT_F + s8 * 8) =
                *(const uint4*)&h2_s[row * H2S_PITCH + s8 * 8];
    }
}

// ---------------- aggregation 2: quarter-wave per node, bf16 h2 + bf16 skip ----------------
__global__ __launch_bounds__(256) void agg2_gather_kernel(const ushortT* __restrict__ h2b,
                                                          const ushortT* __restrict__ skipb,
                                                          const float* __restrict__ b2,
                                                          const float* __restrict__ dinv,
                                                          const int* __restrict__ rowptr,
                                                          const int* __restrict__ csr_src,
                                                          float* __restrict__ out) {
    int node = blockIdx.x * 16 + (threadIdx.x >> 4);
    if (node >= N_NODES) return;
    int l = threadIdx.x & 15;
    const uint2* hp = (const uint2*)h2b;       // 16 uint2 (8B = 4 bf16) per row

    float di = dinv[node];
    float ws = di * di;
    float a[4], g[4];
    bf4_to_f32v(hp[(size_t)node * 16 + l], a);
    float ax = a[0] * ws, ay = a[1] * ws, az = a[2] * ws, aw = a[3] * ws;

    int jb = rowptr[node], je = rowptr[node + 1];
    int j = jb;
    for (; j + 7 < je; j += 8) {
        int s0 = csr_src[j],     s1 = csr_src[j + 1], s2 = csr_src[j + 2], s3 = csr_src[j + 3];
        int s4 = csr_src[j + 4], s5 = csr_src[j + 5], s6 = csr_src[j + 6], s7 = csr_src[j + 7];
        float w0 = dinv[s0] * di, w1 = dinv[s1] * di, w2 = dinv[s2] * di, w3 = dinv[s3] * di;
        float w4 = dinv[s4] * di, w5 = dinv[s5] * di, w6 = dinv[s6] * di, w7 = dinv[s7] * di;
        uint2 u0 = hp[(size_t)s0 * 16 + l];
        uint2 u1 = hp[(size_t)s1 * 16 + l];
        uint2 u2 = hp[(size_t)s2 * 16 + l];
        uint2 u3 = hp[(size_t)s3 * 16 + l];
        uint2 u4 = hp[(size_t)s4 * 16 + l];
        uint2 u5 = hp[(size_t)s5 * 16 + l];
        uint2 u6 = hp[(size_t)s6 * 16 + l];
        uint2 u7 = hp[(size_t)s7 * 16 + l];
        bf4_to_f32v(u0, g);
        ax = fmaf(g[0], w0, ax); ay = fmaf(g[1], w0, ay); az = fmaf(g[2], w0, az); aw = fmaf(g[3], w0, aw);
        bf4_to_f32v(u1, g);
        ax = fmaf(g[0], w1, ax); ay = fmaf(g[1], w1, ay); az = fmaf(g[2], w1, az); aw = fmaf(g[3], w1, aw);
        bf4_to_f32v(u2, g);
        ax = fmaf(g[0], w2, ax); ay = fmaf(g[1], w2, ay); az = fmaf(g[2], w2, az); aw = fmaf(g[3], w2, aw);
        bf4_to_f32v(u3, g);
        ax = fmaf(g[0], w3, ax); ay = fmaf(g[1], w3, ay); az = fmaf(g[2], w3, az); aw = fmaf(g[3], w3, aw);
        bf4_to_f32v(u4, g);
        ax = fmaf(g[0], w4, ax); ay = fmaf(g[1], w4, ay); az = fmaf(g[2], w4, az); aw = fmaf(g[3], w4, aw);
        bf4_to_f32v(u5, g);
        ax = fmaf(g[0], w5, ax); ay = fmaf(g[1], w5, ay); az = fmaf(g[2], w5, az); aw = fmaf(g[3], w5, aw);
        bf4_to_f32v(u6, g);
        ax = fmaf(g[0], w6, ax); ay = fmaf(g[1], w6, ay); az = fmaf(g[2], w6, az); aw = fmaf(g[3], w6, aw);
        bf4_to_f32v(u7, g);
        ax = fmaf(g[0], w7, ax); ay = fmaf(g[1], w7, ay); az = fmaf(g[2], w7, az); aw = fmaf(g[3], w7, aw);
    }
    for (; j + 3 < je; j += 4) {
        int s0 = csr_src[j], s1 = csr_src[j + 1], s2 = csr_src[j + 2], s3 = csr_src[j + 3];
        float w0 = dinv[s0] * di, w1 = dinv[s1] * di, w2 = dinv[s2] * di, w3 = dinv[s3] * di;
        uint2 u0 = hp[(size_t)s0 * 16 + l];
        uint2 u1 = hp[(size_t)s1 * 16 + l];
        uint2 u2 = hp[(size_t)s2 * 16 + l];
        uint2 u3 = hp[(size_t)s3 * 16 + l];
        bf4_to_f32v(u0, g);
        ax = fmaf(g[0], w0, ax); ay = fmaf(g[1], w0, ay); az = fmaf(g[2], w0, az); aw = fmaf(g[3], w0, aw);
        bf4_to_f32v(u1, g);
        ax = fmaf(g[0], w1, ax); ay = fmaf(g[1], w1, ay); az = fmaf(g[2], w1, az); aw = fmaf(g[3], w1, aw);
        bf4_to_f32v(u2, g);
        ax = fmaf(g[0], w2, ax); ay = fmaf(g[1], w2, ay); az = fmaf(g[2], w2, az); aw = fmaf(g[3], w2, aw);
        bf4_to_f32v(u3, g);
        ax = fmaf(g[0], w3, ax); ay = fmaf(g[1], w3, ay); az = fmaf(g[2], w3, az); aw = fmaf(g[3], w3, aw);
    }
    for (; j < je; ++j) {
        int s0 = csr_src[j];
        float w0 = dinv[s0] * di;
        bf4_to_f32v(hp[(size_t)s0 * 16 + l], g);
        ax = fmaf(g[0], w0, ax); ay = fmaf(g[1], w0, ay); az = fmaf(g[2], w0, az); aw = fmaf(g[3], w0, aw);
    }

    float sk[4];
    bf4_to_f32v(((const uint2*)skipb)[(size_t)node * 16 + l], sk);
    float4 bb = ((const float4*)b2)[l];
    float r[4] = {ax + sk[0] + bb.x, ay + sk[1] + bb.y, az + sk[2] + bb.z, aw + sk[3] + bb.w};
    #pragma unroll
    for (int i = 0; i < 4; ++i) {
        float v = r[i];
        if (isnan(v)) v = 0.0f;
        else if (isinf(v)) v = (v > 0.0f) ? 20.0f : -20.0f;
        r[i] = v;
    }
    ((float4*)out)[(size_t)node * 16 + l] = make_float4(r[0], r[1], r[2], r[3]);
}

extern "C" void kernel_launch(void* const* d_in, const int* in_sizes, int n_in,
                              void* d_out, int out_size, void* d_ws, size_t ws_size,
                              hipStream_t stream) {
    const float* x     = (const float*)d_in[0];
    const int*   ei    = (const int*)d_in[1];
    const float* W1    = (const float*)d_in[2];
    const float* b1    = (const float*)d_in[3];
    const float* gamma = (const float*)d_in[4];
    const float* beta  = (const float*)d_in[5];
    const float* W2    = (const float*)d_in[6];
    const float* b2    = (const float*)d_in[7];
    const float* Wskip = (const float*)d_in[8];
    float* out = (float*)d_out;

    const int* src = ei;
    const int* dst = ei + E_EDGES;

    // ws layout
    ushortT* h1b   = (ushortT*)d_ws;                       // N*256 bf16
    ushortT* h2b   = h1b + (size_t)N_NODES * HID_F;        // N*64 bf16
    ushortT* skipb = h2b + (size_t)N_NODES * OUT_F;        // N*64 bf16
    float* dinv    = (float*)(skipb + (size_t)N_NODES * OUT_F);  // N
    ushortT* Bf    = (ushortT*)(dinv + N_NODES);           // 320*512 (fragment order)
    ushortT* W2f   = Bf + (size_t)NCAT * IN_F;             // 64*256 (fragment order)
    int* deg       = (int*)(W2f + (size_t)OUT_F * HID_F);  // N
    int* rowptr    = deg + N_NODES;                        // N+1
    int* cursor    = rowptr + N_NODES + 1;                 // N
    int* csr_src   = cursor + N_NODES;                     // E
    int* bsum      = csr_src + E_EDGES;                    // NSCAN_BLOCKS

    // ---- prep: memset + fused count_deg|wcvt ----
    hipMemsetAsync(deg, 0, N_NODES * sizeof(int), stream);
    prep_kernel<<<CNT_BLOCKS + WCVT_BLOCKS, 256, 0, stream>>>(dst, deg, W1, Wskip, W2,
                                                              Bf, W2f);

    // ---- scan chain (dinv + rowptr + cursor) ----
    scan1_kernel<<<NSCAN_BLOCKS, SB, 0, stream>>>(deg, dinv, rowptr, bsum);
    scan23_kernel<<<(N_NODES + 255) / 256, 256, 0, stream>>>(bsum, rowptr, cursor);

    // ---- fused GEMM1 + scatter ----
    g1scat_kernel<<<FUSED_BLOCKS, 512, 0, stream>>>(x, Bf, h1b, skipb, src, dst,
                                                    cursor, csr_src);

    // ---- fused agg1 + LN + ReLU + GEMM2 -> h2b (32 nodes/block, 1563 blocks) ----
    aggln_g2_kernel<<<NAG_BLOCKS, 256, 0, stream>>>(h1b, dinv, rowptr, csr_src,
                                                    b1, gamma, beta, W2f, h2b);

    // ---- aggregation 2 (bf16 gather, inline weights, fused epilogue) ----
    agg2_gather_kernel<<<(N_NODES + 15) / 16, 256, 0, stream>>>(h2b, skipb, b2, dinv,
                                                                rowptr, csr_src, out);
}